// Round 1
// baseline (374.576 us; speedup 1.0000x reference)
//
#include <hip/hip_runtime.h>

#define D_DIM 4096
#define N_TOK 4096
#define K_EXP 64
#define R_RANK 16
#define KR 1024               // K_EXP * R_RANK
#define SCALE_F 2.0f          // ALPHA / RANK = 32/16

typedef __attribute__((ext_vector_type(8))) short short8_t;   // 8 x bf16 (4 VGPR)
typedef __attribute__((ext_vector_type(4))) float f32x4_t;
typedef __attribute__((ext_vector_type(4))) unsigned short u16x4_t;

__device__ inline unsigned short f2bf(float f) {
  unsigned int u = __builtin_bit_cast(unsigned int, f);
  u += 0x7fffu + ((u >> 16) & 1u);          // RTNE
  return (unsigned short)(u >> 16);
}

// ---------------- pack kernels ----------------
__global__ void pack_f32_to_bf16(const float* __restrict__ in,
                                 unsigned short* __restrict__ out, int n4) {
  int stride = gridDim.x * blockDim.x;
  for (int i = blockIdx.x * blockDim.x + threadIdx.x; i < n4; i += stride) {
    f32x4_t v = *(const f32x4_t*)(in + (size_t)i * 4);
    u16x4_t o;
    o[0] = f2bf(v[0]); o[1] = f2bf(v[1]); o[2] = f2bf(v[2]); o[3] = f2bf(v[3]);
    *(u16x4_t*)(out + (size_t)i * 4) = o;
  }
}

// B (K,D,R) f32  ->  Wb (D, K*R) bf16 : Wb[d][k*16+r] = B[k][d][r]
__global__ void pack_b_kernel(const float* __restrict__ B,
                              unsigned short* __restrict__ Wb, int n) {
  int stride = gridDim.x * blockDim.x;
  for (int i = blockIdx.x * blockDim.x + threadIdx.x; i < n; i += stride) {
    int k   = i >> 14;        // / (4096*4)
    int rem = i & 16383;
    int d   = rem >> 2;
    int r4  = (rem & 3) * 4;
    f32x4_t v = *(const f32x4_t*)(B + ((size_t)(k * D_DIM + d) * R_RANK + r4));
    u16x4_t o;
    o[0] = f2bf(v[0]); o[1] = f2bf(v[1]); o[2] = f2bf(v[2]); o[3] = f2bf(v[3]);
    *(u16x4_t*)(Wb + ((size_t)d * KR + k * R_RANK + r4)) = o;
  }
}

// ---------------- fp32 router scores: scores = x @ Wr^T ----------------
// BM=32 token rows per block, all 64 experts, BK=32. 256 threads.
__global__ __launch_bounds__(256)
void scores_kernel(const float* __restrict__ x, const float* __restrict__ Wr,
                   float* __restrict__ scores) {
  __shared__ float Xs[32][33];
  __shared__ float Ws[64][33];
  int t = threadIdx.x;
  int brow = blockIdx.x * 32;
  int tr = t >> 4, tc = t & 15;
  float acc[2][4] = {};

  for (int k0 = 0; k0 < D_DIM; k0 += 32) {
    int row = t >> 3, c4 = (t & 7) * 4;
    f32x4_t xv = *(const f32x4_t*)(x + (size_t)(brow + row) * D_DIM + k0 + c4);
    f32x4_t w0 = *(const f32x4_t*)(Wr + (size_t)row * D_DIM + k0 + c4);
    f32x4_t w1 = *(const f32x4_t*)(Wr + (size_t)(row + 32) * D_DIM + k0 + c4);
    __syncthreads();
    Xs[row][c4 + 0] = xv[0]; Xs[row][c4 + 1] = xv[1];
    Xs[row][c4 + 2] = xv[2]; Xs[row][c4 + 3] = xv[3];
    Ws[row][c4 + 0] = w0[0]; Ws[row][c4 + 1] = w0[1];
    Ws[row][c4 + 2] = w0[2]; Ws[row][c4 + 3] = w0[3];
    Ws[row + 32][c4 + 0] = w1[0]; Ws[row + 32][c4 + 1] = w1[1];
    Ws[row + 32][c4 + 2] = w1[2]; Ws[row + 32][c4 + 3] = w1[3];
    __syncthreads();
#pragma unroll
    for (int kk = 0; kk < 32; ++kk) {
      float a0 = Xs[tr * 2][kk], a1 = Xs[tr * 2 + 1][kk];
      float b0 = Ws[tc * 4 + 0][kk], b1 = Ws[tc * 4 + 1][kk];
      float b2 = Ws[tc * 4 + 2][kk], b3 = Ws[tc * 4 + 3][kk];
      acc[0][0] += a0 * b0; acc[0][1] += a0 * b1; acc[0][2] += a0 * b2; acc[0][3] += a0 * b3;
      acc[1][0] += a1 * b0; acc[1][1] += a1 * b1; acc[1][2] += a1 * b2; acc[1][3] += a1 * b3;
    }
  }
#pragma unroll
  for (int i = 0; i < 2; ++i)
#pragma unroll
    for (int j = 0; j < 4; ++j)
      scores[(size_t)(brow + tr * 2 + i) * K_EXP + tc * 4 + j] = acc[i][j];
}

// ---------------- per-token top-16 + softmax -> dense G (N,64) ----------------
__global__ void topk_kernel(const float* __restrict__ scores, float* __restrict__ G) {
  int wid = threadIdx.x >> 6, lane = threadIdx.x & 63;
  int n = blockIdx.x * 4 + wid;
  float rem = scores[(size_t)n * K_EXP + lane];
  float topv[16]; int topi[16];
#pragma unroll
  for (int it = 0; it < 16; ++it) {
    float bv = rem; int bi = lane;
#pragma unroll
    for (int off = 32; off >= 1; off >>= 1) {
      float ov = __shfl_xor(bv, off);
      int oi = __shfl_xor(bi, off);
      if (ov > bv || (ov == bv && oi < bi)) { bv = ov; bi = oi; }
    }
    topv[it] = bv; topi[it] = bi;
    if (lane == bi) rem = -1e30f;
  }
  float mx = topv[0];
  float s = 0.f;
#pragma unroll
  for (int j = 0; j < 16; ++j) s += expf(topv[j] - mx);
  float g = 0.f;
#pragma unroll
  for (int j = 0; j < 16; ++j)
    if (topi[j] == lane) g = expf(topv[j] - mx) / s;
  G[(size_t)n * K_EXP + lane] = g;
}

// ---------------- bf16 MFMA GEMM: C = Aop(M,Kd) * Bop(N,Kd)^T ----------------
// 128x128 tile, BK=32, 256 threads = 4 waves (2x2), 4x4 frags/wave.
// EPI 0: v *= G[row][col>>4], store bf16 to Cout (N-stride).  EPI 1: v *= SCALE_F, store f32.
template <int EPI>
__global__ __launch_bounds__(256)
void gemm_bt(const unsigned short* __restrict__ Aop, const unsigned short* __restrict__ Bop,
             void* __restrict__ Cout, const float* __restrict__ G,
             int M, int N, int Kd) {
  __shared__ unsigned short As[128 * 32];
  __shared__ unsigned short Bs[128 * 32];
  int t = threadIdx.x;
  int bcol = blockIdx.x * 128;
  int brow = blockIdx.y * 128;
  int wid = t >> 6, lane = t & 63;
  int wr = wid >> 1, wc = wid & 1;
  int lr = lane & 15, kh = lane >> 4;

  int r0 = t >> 2, c0 = (t & 3) * 8;   // staging: 16B segs, rows 0..63 / 64..127
  int r1 = r0 + 64;

  const unsigned short* Ag = Aop + (size_t)brow * Kd;
  const unsigned short* Bg = Bop + (size_t)bcol * Kd;

  f32x4_t acc[4][4] = {};

  for (int k0 = 0; k0 < Kd; k0 += 32) {
    short8_t a0 = *(const short8_t*)(Ag + (size_t)r0 * Kd + k0 + c0);
    short8_t a1 = *(const short8_t*)(Ag + (size_t)r1 * Kd + k0 + c0);
    short8_t b0 = *(const short8_t*)(Bg + (size_t)r0 * Kd + k0 + c0);
    short8_t b1 = *(const short8_t*)(Bg + (size_t)r1 * Kd + k0 + c0);
    __syncthreads();
    *(short8_t*)(As + r0 * 32 + c0) = a0;
    *(short8_t*)(As + r1 * 32 + c0) = a1;
    *(short8_t*)(Bs + r0 * 32 + c0) = b0;
    *(short8_t*)(Bs + r1 * 32 + c0) = b1;
    __syncthreads();
    short8_t af[4], bfv[4];
#pragma unroll
    for (int m = 0; m < 4; ++m)
      af[m] = *(const short8_t*)(As + (wr * 64 + m * 16 + lr) * 32 + kh * 8);
#pragma unroll
    for (int n = 0; n < 4; ++n)
      bfv[n] = *(const short8_t*)(Bs + (wc * 64 + n * 16 + lr) * 32 + kh * 8);
#pragma unroll
    for (int m = 0; m < 4; ++m)
#pragma unroll
      for (int n = 0; n < 4; ++n)
        acc[m][n] = __builtin_amdgcn_mfma_f32_16x16x32_bf16(af[m], bfv[n], acc[m][n], 0, 0, 0);
  }

#pragma unroll
  for (int m = 0; m < 4; ++m) {
    int gr0 = brow + wr * 64 + m * 16 + kh * 4;   // C/D: row=(lane>>4)*4+j, col=lane&15
#pragma unroll
    for (int n = 0; n < 4; ++n) {
      int gc = bcol + wc * 64 + n * 16 + lr;
#pragma unroll
      for (int j = 0; j < 4; ++j) {
        int row = gr0 + j;
        float v = acc[m][n][j];
        if constexpr (EPI == 0) {
          v *= G[(size_t)row * K_EXP + (gc >> 4)];
          ((unsigned short*)Cout)[(size_t)row * N + gc] = f2bf(v);
        } else {
          ((float*)Cout)[(size_t)row * N + gc] = v * SCALE_F;
        }
      }
    }
  }
}

// ---------------- launch ----------------
extern "C" void kernel_launch(void* const* d_in, const int* in_sizes, int n_in,
                              void* d_out, int out_size, void* d_ws, size_t ws_size,
                              hipStream_t stream) {
  const float* x  = (const float*)d_in[0];   // (2,2048,4096)
  const float* A  = (const float*)d_in[1];   // (64,16,4096)
  const float* B  = (const float*)d_in[2];   // (64,4096,16)
  const float* Wr = (const float*)d_in[3];   // (64,4096)
  float* out = (float*)d_out;

  char* ws = (char*)d_ws;
  size_t off = 0;
  auto alloc = [&](size_t bytes) { void* p = ws + off; off += (bytes + 255) & ~255ull; return p; };
  float*          scores = (float*)alloc((size_t)N_TOK * K_EXP * 4);
  float*          G      = (float*)alloc((size_t)N_TOK * K_EXP * 4);
  unsigned short* Xb     = (unsigned short*)alloc((size_t)N_TOK * D_DIM * 2);
  unsigned short* Ab     = (unsigned short*)alloc((size_t)KR * D_DIM * 2);
  unsigned short* Wb     = (unsigned short*)alloc((size_t)D_DIM * KR * 2);
  unsigned short* Hgb    = (unsigned short*)alloc((size_t)N_TOK * KR * 2);
  (void)ws_size; (void)in_sizes; (void)n_in; (void)out_size;

  pack_f32_to_bf16<<<2048, 256, 0, stream>>>(x, Xb, N_TOK * D_DIM / 4);
  pack_f32_to_bf16<<<1024, 256, 0, stream>>>(A, Ab, KR * D_DIM / 4);
  pack_b_kernel<<<1024, 256, 0, stream>>>(B, Wb, K_EXP * D_DIM * 4);
  scores_kernel<<<N_TOK / 32, 256, 0, stream>>>(x, Wr, scores);
  topk_kernel<<<N_TOK / 4, 256, 0, stream>>>(scores, G);

  // H_gated(bf16, N_TOK x KR) = (X @ A_all^T) * G
  gemm_bt<0><<<dim3(KR / 128, N_TOK / 128), 256, 0, stream>>>(Xb, Ab, Hgb, G, N_TOK, KR, D_DIM);
  // out(f32) = SCALE * Hg @ Wb^T
  gemm_bt<1><<<dim3(D_DIM / 128, N_TOK / 128), 256, 0, stream>>>(Hgb, Wb, out, nullptr, N_TOK, D_DIM, KR);
}

// Round 2
// 214.123 us; speedup vs baseline: 1.7493x; 1.7493x over previous
//
#include <hip/hip_runtime.h>

#define D_DIM 4096
#define N_TOK 4096
#define K_EXP 64
#define R_RANK 16
#define KR 1024               // K_EXP * R_RANK
#define SCALE_F 2.0f          // ALPHA / RANK
#define SPLIT_S 8
#define KC_S (D_DIM / SPLIT_S)   // 512

typedef __attribute__((ext_vector_type(8))) short short8_t;   // 8 x bf16
typedef __attribute__((ext_vector_type(4))) float f32x4_t;
typedef __attribute__((ext_vector_type(4))) unsigned short u16x4_t;

__device__ __forceinline__ unsigned short f2bf(float f) {
  unsigned int u = __builtin_bit_cast(unsigned int, f);
  u += 0x7fffu + ((u >> 16) & 1u);          // RTNE
  return (unsigned short)(u >> 16);
}
__device__ __forceinline__ float bf2f(unsigned short h) {
  return __builtin_bit_cast(float, ((unsigned int)h) << 16);
}

// async global->LDS, 16B per lane. LDS dest must be wave-uniform base + lane*16.
__device__ __forceinline__ void gload16(const void* g, void* l) {
  __builtin_amdgcn_global_load_lds(
      (const __attribute__((address_space(1))) unsigned int*)g,
      (__attribute__((address_space(3))) unsigned int*)l, 16, 0, 0);
}

// ---------------- pack kernels ----------------
__global__ void pack_f32_to_bf16(const float* __restrict__ in,
                                 unsigned short* __restrict__ out, int n4) {
  int stride = gridDim.x * blockDim.x;
  for (int i = blockIdx.x * blockDim.x + threadIdx.x; i < n4; i += stride) {
    f32x4_t v = *(const f32x4_t*)(in + (size_t)i * 4);
    u16x4_t o;
    o[0] = f2bf(v[0]); o[1] = f2bf(v[1]); o[2] = f2bf(v[2]); o[3] = f2bf(v[3]);
    *(u16x4_t*)(out + (size_t)i * 4) = o;
  }
}

// B (K,D,R) f32 -> Wb (D, K*R) bf16 : Wb[d][k*16+r] = B[k][d][r]
__global__ void pack_b_kernel(const float* __restrict__ B,
                              unsigned short* __restrict__ Wb, int n) {
  int stride = gridDim.x * blockDim.x;
  for (int i = blockIdx.x * blockDim.x + threadIdx.x; i < n; i += stride) {
    int k   = i >> 14;
    int rem = i & 16383;
    int d   = rem >> 2;
    int r4  = (rem & 3) * 4;
    f32x4_t v = *(const f32x4_t*)(B + ((size_t)(k * D_DIM + d) * R_RANK + r4));
    u16x4_t o;
    o[0] = f2bf(v[0]); o[1] = f2bf(v[1]); o[2] = f2bf(v[2]); o[3] = f2bf(v[3]);
    *(u16x4_t*)(Wb + ((size_t)d * KR + k * R_RANK + r4)) = o;
  }
}

// ---------------- router scores via MFMA, hi/lo bf16 split, split-K ----------------
// P[kc][n][e] partial of x @ Wr^T over K-chunk kc. Converts fp32->hi/lo bf16 in-kernel.
__global__ __launch_bounds__(256)
void scores_mfma(const float* __restrict__ x, const float* __restrict__ Wr,
                 float* __restrict__ P) {
  __shared__ unsigned short Ah[128 * 32];
  __shared__ unsigned short Al[128 * 32];
  __shared__ unsigned short Bh[64 * 32];
  __shared__ unsigned short Bl[64 * 32];
  int t = threadIdx.x;
  int brow = blockIdx.x * 128;
  int kcb = blockIdx.y * KC_S;
  int wid = t >> 6, lane = t & 63;
  int wr = wid >> 1, wc = wid & 1;
  int lr = lane & 15, kh = lane >> 4;

  f32x4_t acc[4][2] = {};

  for (int k0 = kcb; k0 < kcb + KC_S; k0 += 32) {
    f32x4_t av[4];
#pragma unroll
    for (int i = 0; i < 4; ++i) {
      int s = t * 4 + i;                       // 0..1023: row=s>>3 (0..127), col4=(s&7)*4
      av[i] = *(const f32x4_t*)(x + (size_t)(brow + (s >> 3)) * D_DIM + k0 + (s & 7) * 4);
    }
    f32x4_t wv[2];
#pragma unroll
    for (int i = 0; i < 2; ++i) {
      int s = t * 2 + i;                       // 0..511: row=s>>3 (0..63)
      wv[i] = *(const f32x4_t*)(Wr + (size_t)(s >> 3) * D_DIM + k0 + (s & 7) * 4);
    }
    __syncthreads();                           // prev step's frag reads done
#pragma unroll
    for (int i = 0; i < 4; ++i) {
      int s = t * 4 + i; int row = s >> 3, c = (s & 7) * 4;
      u16x4_t h, l;
#pragma unroll
      for (int j = 0; j < 4; ++j) { h[j] = f2bf(av[i][j]); l[j] = f2bf(av[i][j] - bf2f(h[j])); }
      *(u16x4_t*)(Ah + row * 32 + c) = h;
      *(u16x4_t*)(Al + row * 32 + c) = l;
    }
#pragma unroll
    for (int i = 0; i < 2; ++i) {
      int s = t * 2 + i; int row = s >> 3, c = (s & 7) * 4;
      u16x4_t h, l;
#pragma unroll
      for (int j = 0; j < 4; ++j) { h[j] = f2bf(wv[i][j]); l[j] = f2bf(wv[i][j] - bf2f(h[j])); }
      *(u16x4_t*)(Bh + row * 32 + c) = h;
      *(u16x4_t*)(Bl + row * 32 + c) = l;
    }
    __syncthreads();
    short8_t ah[4], al[4], bh[2], bl[2];
#pragma unroll
    for (int m = 0; m < 4; ++m) {
      ah[m] = *(const short8_t*)(Ah + (wr * 64 + m * 16 + lr) * 32 + kh * 8);
      al[m] = *(const short8_t*)(Al + (wr * 64 + m * 16 + lr) * 32 + kh * 8);
    }
#pragma unroll
    for (int n = 0; n < 2; ++n) {
      bh[n] = *(const short8_t*)(Bh + (wc * 32 + n * 16 + lr) * 32 + kh * 8);
      bl[n] = *(const short8_t*)(Bl + (wc * 32 + n * 16 + lr) * 32 + kh * 8);
    }
#pragma unroll
    for (int m = 0; m < 4; ++m)
#pragma unroll
      for (int n = 0; n < 2; ++n) {
        acc[m][n] = __builtin_amdgcn_mfma_f32_16x16x32_bf16(ah[m], bh[n], acc[m][n], 0, 0, 0);
        acc[m][n] = __builtin_amdgcn_mfma_f32_16x16x32_bf16(al[m], bh[n], acc[m][n], 0, 0, 0);
        acc[m][n] = __builtin_amdgcn_mfma_f32_16x16x32_bf16(ah[m], bl[n], acc[m][n], 0, 0, 0);
      }
  }

  float* Pb = P + (size_t)blockIdx.y * N_TOK * K_EXP;
#pragma unroll
  for (int m = 0; m < 4; ++m)
#pragma unroll
    for (int n = 0; n < 2; ++n)
#pragma unroll
      for (int j = 0; j < 4; ++j) {
        int row = brow + wr * 64 + m * 16 + kh * 4 + j;
        int e = wc * 32 + n * 16 + lr;
        Pb[(size_t)row * K_EXP + e] = acc[m][n][j];
      }
}

// ---------------- per-token top-16 + softmax -> dense G (N,64) ----------------
__global__ void topk_kernel(const float* __restrict__ P, float* __restrict__ G) {
  int wid = threadIdx.x >> 6, lane = threadIdx.x & 63;
  int n = blockIdx.x * 4 + wid;
  float rem = 0.f;
#pragma unroll
  for (int c = 0; c < SPLIT_S; ++c)
    rem += P[((size_t)c * N_TOK + n) * K_EXP + lane];
  float topv[16]; int topi[16];
#pragma unroll
  for (int it = 0; it < 16; ++it) {
    float bv = rem; int bi = lane;
#pragma unroll
    for (int off = 32; off >= 1; off >>= 1) {
      float ov = __shfl_xor(bv, off);
      int oi = __shfl_xor(bi, off);
      if (ov > bv || (ov == bv && oi < bi)) { bv = ov; bi = oi; }
    }
    topv[it] = bv; topi[it] = bi;
    if (lane == bi) rem = -1e30f;
  }
  float mx = topv[0];
  float s = 0.f;
#pragma unroll
  for (int j = 0; j < 16; ++j) s += expf(topv[j] - mx);
  float g = 0.f;
#pragma unroll
  for (int j = 0; j < 16; ++j)
    if (topi[j] == lane) g = expf(topv[j] - mx) / s;
  G[(size_t)n * K_EXP + lane] = g;
}

// ---------------- bf16 MFMA GEMM: C = Aop(M,Kd) * Bop(N,Kd)^T ----------------
// 128x128 tile, BK=32, 4 waves (2x2), 4x4 frags/wave, global_load_lds width-16 staging.
template <int EPI>
__global__ __launch_bounds__(256)
void gemm_bt(const unsigned short* __restrict__ Aop, const unsigned short* __restrict__ Bop,
             void* __restrict__ Cout, const float* __restrict__ G,
             int M, int N, int Kd) {
  __shared__ unsigned short As[128 * 32];
  __shared__ unsigned short Bs[128 * 32];
  int t = threadIdx.x;
  int bcol = blockIdx.x * 128;
  int brow = blockIdx.y * 128;
  int wid = t >> 6, lane = t & 63;
  int wr = wid >> 1, wc = wid & 1;
  int lr = lane & 15, kh = lane >> 4;

  // staging: wave wid loads rows [wid*16, wid*16+16) and [64+wid*16, ...), lane -> (row lane>>2, col (lane&3)*8)
  const unsigned short* Ag = Aop + (size_t)(brow + wid * 16 + (lane >> 2)) * Kd + (lane & 3) * 8;
  const unsigned short* Bg = Bop + (size_t)(bcol + wid * 16 + (lane >> 2)) * Kd + (lane & 3) * 8;
  unsigned short* Asl0 = As + wid * 512 + lane * 8;
  unsigned short* Asl1 = As + (wid + 4) * 512 + lane * 8;
  unsigned short* Bsl0 = Bs + wid * 512 + lane * 8;
  unsigned short* Bsl1 = Bs + (wid + 4) * 512 + lane * 8;
  const size_t half = (size_t)64 * Kd;

  f32x4_t acc[4][4] = {};

  for (int k0 = 0; k0 < Kd; k0 += 32) {
    gload16(Ag + k0, Asl0);
    gload16(Ag + half + k0, Asl1);
    gload16(Bg + k0, Bsl0);
    gload16(Bg + half + k0, Bsl1);
    __syncthreads();                  // vmcnt(0) drained before barrier -> LDS ready
    short8_t af[4], bfv[4];
#pragma unroll
    for (int m = 0; m < 4; ++m)
      af[m] = *(const short8_t*)(As + (wr * 64 + m * 16 + lr) * 32 + kh * 8);
#pragma unroll
    for (int n = 0; n < 4; ++n)
      bfv[n] = *(const short8_t*)(Bs + (wc * 64 + n * 16 + lr) * 32 + kh * 8);
#pragma unroll
    for (int m = 0; m < 4; ++m)
#pragma unroll
      for (int n = 0; n < 4; ++n)
        acc[m][n] = __builtin_amdgcn_mfma_f32_16x16x32_bf16(af[m], bfv[n], acc[m][n], 0, 0, 0);
    __syncthreads();                  // frag reads done before next-step overwrite
  }

#pragma unroll
  for (int m = 0; m < 4; ++m) {
    int gr0 = brow + wr * 64 + m * 16 + kh * 4;
#pragma unroll
    for (int n = 0; n < 4; ++n) {
      int gc = bcol + wc * 64 + n * 16 + lr;
#pragma unroll
      for (int j = 0; j < 4; ++j) {
        int row = gr0 + j;
        float v = acc[m][n][j];
        if constexpr (EPI == 0) {
          v *= G[(size_t)row * K_EXP + (gc >> 4)];
          ((unsigned short*)Cout)[(size_t)row * N + gc] = f2bf(v);
        } else {
          ((float*)Cout)[(size_t)row * N + gc] = v * SCALE_F;
        }
      }
    }
  }
}

// ---------------- launch ----------------
extern "C" void kernel_launch(void* const* d_in, const int* in_sizes, int n_in,
                              void* d_out, int out_size, void* d_ws, size_t ws_size,
                              hipStream_t stream) {
  const float* x  = (const float*)d_in[0];   // (2,2048,4096)
  const float* A  = (const float*)d_in[1];   // (64,16,4096)
  const float* B  = (const float*)d_in[2];   // (64,4096,16)
  const float* Wr = (const float*)d_in[3];   // (64,4096)
  float* out = (float*)d_out;

  char* ws = (char*)d_ws;
  size_t off = 0;
  auto alloc = [&](size_t bytes) { void* p = ws + off; off += (bytes + 255) & ~255ull; return p; };
  float*          P   = (float*)alloc((size_t)SPLIT_S * N_TOK * K_EXP * 4);  // 8 MB
  float*          G   = (float*)alloc((size_t)N_TOK * K_EXP * 4);
  unsigned short* Xb  = (unsigned short*)alloc((size_t)N_TOK * D_DIM * 2);   // 32 MB
  unsigned short* Ab  = (unsigned short*)alloc((size_t)KR * D_DIM * 2);      // 8 MB
  unsigned short* Wb  = (unsigned short*)alloc((size_t)D_DIM * KR * 2);      // 8 MB
  unsigned short* Hgb = (unsigned short*)alloc((size_t)N_TOK * KR * 2);      // 8 MB
  (void)ws_size; (void)in_sizes; (void)n_in; (void)out_size;

  pack_f32_to_bf16<<<2048, 256, 0, stream>>>(x, Xb, N_TOK * D_DIM / 4);
  pack_f32_to_bf16<<<1024, 256, 0, stream>>>(A, Ab, KR * D_DIM / 4);
  pack_b_kernel<<<1024, 256, 0, stream>>>(B, Wb, K_EXP * D_DIM * 4);

  scores_mfma<<<dim3(N_TOK / 128, SPLIT_S), 256, 0, stream>>>(x, Wr, P);
  topk_kernel<<<N_TOK / 4, 256, 0, stream>>>(P, G);

  // H_gated(bf16, N_TOK x KR) = (X @ A_all^T) * G
  gemm_bt<0><<<dim3(KR / 128, N_TOK / 128), 256, 0, stream>>>(Xb, Ab, Hgb, G, N_TOK, KR, D_DIM);
  // out(f32) = SCALE * Hg @ Wb^T
  gemm_bt<1><<<dim3(D_DIM / 128, N_TOK / 128), 256, 0, stream>>>(Hgb, Wb, out, nullptr, N_TOK, D_DIM, KR);
}

// Round 3
// 168.226 us; speedup vs baseline: 2.2266x; 1.2728x over previous
//
#include <hip/hip_runtime.h>

#define D_DIM 4096
#define N_TOK 4096
#define K_EXP 64
#define R_RANK 16
#define KR 1024               // K_EXP * R_RANK
#define SCALE_F 2.0f          // ALPHA / RANK
#define SPLIT_S 16
#define KC_S (D_DIM / SPLIT_S)   // 256
#define SPLIT_G 2
#define KC_G (D_DIM / SPLIT_G)   // 2048

typedef __attribute__((ext_vector_type(8))) short short8_t;   // 8 x bf16
typedef __attribute__((ext_vector_type(4))) float f32x4_t;
typedef __attribute__((ext_vector_type(4))) unsigned short u16x4_t;

__device__ __forceinline__ unsigned short f2bf(float f) {
  unsigned int u = __builtin_bit_cast(unsigned int, f);
  u += 0x7fffu + ((u >> 16) & 1u);          // RTNE
  return (unsigned short)(u >> 16);
}
__device__ __forceinline__ float bf2f(unsigned short h) {
  return __builtin_bit_cast(float, ((unsigned int)h) << 16);
}

// async global->LDS, 16B per lane. LDS dest must be wave-uniform base + lane*16.
__device__ __forceinline__ void gload16(const void* g, void* l) {
  __builtin_amdgcn_global_load_lds(
      (const __attribute__((address_space(1))) unsigned int*)g,
      (__attribute__((address_space(3))) unsigned int*)l, 16, 0, 0);
}

// ---------------- pack kernels ----------------
__global__ void pack_f32_to_bf16(const float* __restrict__ in,
                                 unsigned short* __restrict__ out, int n4) {
  int stride = gridDim.x * blockDim.x;
  for (int i = blockIdx.x * blockDim.x + threadIdx.x; i < n4; i += stride) {
    f32x4_t v = *(const f32x4_t*)(in + (size_t)i * 4);
    u16x4_t o;
    o[0] = f2bf(v[0]); o[1] = f2bf(v[1]); o[2] = f2bf(v[2]); o[3] = f2bf(v[3]);
    *(u16x4_t*)(out + (size_t)i * 4) = o;
  }
}

// B (K,D,R) f32 -> Wb (D, K*R) bf16 : Wb[d][k*16+r] = B[k][d][r]
__global__ void pack_b_kernel(const float* __restrict__ B,
                              unsigned short* __restrict__ Wb, int n) {
  int stride = gridDim.x * blockDim.x;
  for (int i = blockIdx.x * blockDim.x + threadIdx.x; i < n; i += stride) {
    int k   = i >> 14;
    int rem = i & 16383;
    int d   = rem >> 2;
    int r4  = (rem & 3) * 4;
    f32x4_t v = *(const f32x4_t*)(B + ((size_t)(k * D_DIM + d) * R_RANK + r4));
    u16x4_t o;
    o[0] = f2bf(v[0]); o[1] = f2bf(v[1]); o[2] = f2bf(v[2]); o[3] = f2bf(v[3]);
    *(u16x4_t*)(Wb + ((size_t)d * KR + k * R_RANK + r4)) = o;
  }
}

// ---------------- router scores via MFMA (hi/lo bf16 split, split-K=16) ----------------
// Also emits Xb (bf16 hi) for the big GEMM — each (row,k) tile is loaded exactly once here.
__global__ __launch_bounds__(256)
void scores_mfma(const float* __restrict__ x, const float* __restrict__ Wr,
                 float* __restrict__ P, unsigned short* __restrict__ Xb) {
  __shared__ unsigned short Ah[128 * 32];
  __shared__ unsigned short Al[128 * 32];
  __shared__ unsigned short Bh[64 * 32];
  __shared__ unsigned short Bl[64 * 32];
  int t = threadIdx.x;
  int brow = blockIdx.x * 128;
  int kcb = blockIdx.y * KC_S;
  int wid = t >> 6, lane = t & 63;
  int wr = wid >> 1, wc = wid & 1;
  int lr = lane & 15, kh = lane >> 4;

  f32x4_t acc[4][2] = {};

  for (int k0 = kcb; k0 < kcb + KC_S; k0 += 32) {
    f32x4_t av[4];
#pragma unroll
    for (int i = 0; i < 4; ++i) {
      int s = t * 4 + i;                       // row=s>>3 (0..127), col4=(s&7)*4
      av[i] = *(const f32x4_t*)(x + (size_t)(brow + (s >> 3)) * D_DIM + k0 + (s & 7) * 4);
    }
    f32x4_t wv[2];
#pragma unroll
    for (int i = 0; i < 2; ++i) {
      int s = t * 2 + i;                       // row=s>>3 (0..63)
      wv[i] = *(const f32x4_t*)(Wr + (size_t)(s >> 3) * D_DIM + k0 + (s & 7) * 4);
    }
    __syncthreads();                           // prev step's frag reads done
#pragma unroll
    for (int i = 0; i < 4; ++i) {
      int s = t * 4 + i; int row = s >> 3, c = (s & 7) * 4;
      u16x4_t h, l;
#pragma unroll
      for (int j = 0; j < 4; ++j) { h[j] = f2bf(av[i][j]); l[j] = f2bf(av[i][j] - bf2f(h[j])); }
      *(u16x4_t*)(Ah + row * 32 + c) = h;
      *(u16x4_t*)(Al + row * 32 + c) = l;
      *(u16x4_t*)(Xb + (size_t)(brow + row) * D_DIM + k0 + c) = h;   // fused x->bf16 pack
    }
#pragma unroll
    for (int i = 0; i < 2; ++i) {
      int s = t * 2 + i; int row = s >> 3, c = (s & 7) * 4;
      u16x4_t h, l;
#pragma unroll
      for (int j = 0; j < 4; ++j) { h[j] = f2bf(wv[i][j]); l[j] = f2bf(wv[i][j] - bf2f(h[j])); }
      *(u16x4_t*)(Bh + row * 32 + c) = h;
      *(u16x4_t*)(Bl + row * 32 + c) = l;
    }
    __syncthreads();
    short8_t ah[4], al[4], bh[2], bl[2];
#pragma unroll
    for (int m = 0; m < 4; ++m) {
      ah[m] = *(const short8_t*)(Ah + (wr * 64 + m * 16 + lr) * 32 + kh * 8);
      al[m] = *(const short8_t*)(Al + (wr * 64 + m * 16 + lr) * 32 + kh * 8);
    }
#pragma unroll
    for (int n = 0; n < 2; ++n) {
      bh[n] = *(const short8_t*)(Bh + (wc * 32 + n * 16 + lr) * 32 + kh * 8);
      bl[n] = *(const short8_t*)(Bl + (wc * 32 + n * 16 + lr) * 32 + kh * 8);
    }
#pragma unroll
    for (int m = 0; m < 4; ++m)
#pragma unroll
      for (int n = 0; n < 2; ++n) {
        acc[m][n] = __builtin_amdgcn_mfma_f32_16x16x32_bf16(ah[m], bh[n], acc[m][n], 0, 0, 0);
        acc[m][n] = __builtin_amdgcn_mfma_f32_16x16x32_bf16(al[m], bh[n], acc[m][n], 0, 0, 0);
        acc[m][n] = __builtin_amdgcn_mfma_f32_16x16x32_bf16(ah[m], bl[n], acc[m][n], 0, 0, 0);
      }
  }

  float* Pb = P + (size_t)blockIdx.y * N_TOK * K_EXP;
#pragma unroll
  for (int m = 0; m < 4; ++m)
#pragma unroll
    for (int n = 0; n < 2; ++n)
#pragma unroll
      for (int j = 0; j < 4; ++j) {
        int row = brow + wr * 64 + m * 16 + kh * 4 + j;
        int e = wc * 32 + n * 16 + lr;
        Pb[(size_t)row * K_EXP + e] = acc[m][n][j];
      }
}

// ---------------- per-token top-16 + softmax -> dense G (N,64) ----------------
__global__ void topk_kernel(const float* __restrict__ P, float* __restrict__ G) {
  int wid = threadIdx.x >> 6, lane = threadIdx.x & 63;
  int n = blockIdx.x * 4 + wid;
  float rem = 0.f;
#pragma unroll
  for (int c = 0; c < SPLIT_S; ++c)
    rem += P[((size_t)c * N_TOK + n) * K_EXP + lane];
  float topv[16]; int topi[16];
#pragma unroll
  for (int it = 0; it < 16; ++it) {
    float bv = rem; int bi = lane;
#pragma unroll
    for (int off = 32; off >= 1; off >>= 1) {
      float ov = __shfl_xor(bv, off);
      int oi = __shfl_xor(bi, off);
      if (ov > bv || (ov == bv && oi < bi)) { bv = ov; bi = oi; }
    }
    topv[it] = bv; topi[it] = bi;
    if (lane == bi) rem = -1e30f;
  }
  float mx = topv[0];
  float s = 0.f;
#pragma unroll
  for (int j = 0; j < 16; ++j) s += expf(topv[j] - mx);
  float g = 0.f;
#pragma unroll
  for (int j = 0; j < 16; ++j)
    if (topi[j] == lane) g = expf(topv[j] - mx) / s;
  G[(size_t)n * K_EXP + lane] = g;
}

// ---------------- GEMM1 split-K: Pg[z] = Xb * Ab^T over K-chunk z ----------------
// 128x128 tile, BK=32, 512 blocks (8 N x 32 M x 2 z), XCD-bijective swizzle.
__global__ __launch_bounds__(256)
void gemm1_split(const unsigned short* __restrict__ Aop, const unsigned short* __restrict__ Bop,
                 float* __restrict__ Pg) {
  __shared__ unsigned short As[128 * 32];
  __shared__ unsigned short Bs[128 * 32];
  int b = blockIdx.x;                       // nwg = 512
  int logical = (b & 7) * 64 + (b >> 3);    // bijective XCD remap (nwg%8==0)
  int xb = logical & 7;                     // N-dim (KR/128)
  int yb = (logical >> 3) & 31;             // M-dim (tokens/128)
  int zb = logical >> 8;                    // K split
  int bcol = xb * 128, brow = yb * 128;
  int kbeg = zb * KC_G;

  int t = threadIdx.x;
  int wid = t >> 6, lane = t & 63;
  int wr = wid >> 1, wc = wid & 1;
  int lr = lane & 15, kh = lane >> 4;

  const unsigned short* Ag = Aop + (size_t)(brow + wid * 16 + (lane >> 2)) * D_DIM + (lane & 3) * 8;
  const unsigned short* Bg = Bop + (size_t)(bcol + wid * 16 + (lane >> 2)) * D_DIM + (lane & 3) * 8;
  unsigned short* Asl0 = As + wid * 512 + lane * 8;
  unsigned short* Asl1 = As + (wid + 4) * 512 + lane * 8;
  unsigned short* Bsl0 = Bs + wid * 512 + lane * 8;
  unsigned short* Bsl1 = Bs + (wid + 4) * 512 + lane * 8;
  const size_t half = (size_t)64 * D_DIM;

  f32x4_t acc[4][4] = {};

  for (int k0 = kbeg; k0 < kbeg + KC_G; k0 += 32) {
    gload16(Ag + k0, Asl0);
    gload16(Ag + half + k0, Asl1);
    gload16(Bg + k0, Bsl0);
    gload16(Bg + half + k0, Bsl1);
    __syncthreads();
    short8_t af[4], bfv[4];
#pragma unroll
    for (int m = 0; m < 4; ++m)
      af[m] = *(const short8_t*)(As + (wr * 64 + m * 16 + lr) * 32 + kh * 8);
#pragma unroll
    for (int n = 0; n < 4; ++n)
      bfv[n] = *(const short8_t*)(Bs + (wc * 64 + n * 16 + lr) * 32 + kh * 8);
#pragma unroll
    for (int m = 0; m < 4; ++m)
#pragma unroll
      for (int n = 0; n < 4; ++n)
        acc[m][n] = __builtin_amdgcn_mfma_f32_16x16x32_bf16(af[m], bfv[n], acc[m][n], 0, 0, 0);
    __syncthreads();
  }

  float* Pz = Pg + (size_t)zb * N_TOK * KR;
#pragma unroll
  for (int m = 0; m < 4; ++m) {
    int gr0 = brow + wr * 64 + m * 16 + kh * 4;
#pragma unroll
    for (int n = 0; n < 4; ++n) {
      int gc = bcol + wc * 64 + n * 16 + lr;
#pragma unroll
      for (int j = 0; j < 4; ++j)
        Pz[(size_t)(gr0 + j) * KR + gc] = acc[m][n][j];
    }
  }
}

// ---------------- reduce split-K partials, apply gate, pack bf16 ----------------
__global__ void reduce_gate_pack(const float* __restrict__ Pg, const float* __restrict__ G,
                                 unsigned short* __restrict__ Hgb) {
  int idx4 = blockIdx.x * blockDim.x + threadIdx.x;   // 1M threads, 4 elems each
  size_t i = (size_t)idx4 * 4;
  int n = (int)(i >> 10);
  int kr = (int)(i & 1023);
  float g = G[(size_t)n * K_EXP + (kr >> 4)];
  f32x4_t v0 = *(const f32x4_t*)(Pg + i);
  f32x4_t v1 = *(const f32x4_t*)(Pg + (size_t)N_TOK * KR + i);
  u16x4_t o;
#pragma unroll
  for (int j = 0; j < 4; ++j) o[j] = f2bf((v0[j] + v1[j]) * g);
  *(u16x4_t*)(Hgb + i) = o;
}

// ---------------- GEMM2: out = SCALE * Hgb(M,KR) * Wb(N,KR)^T, f32 out ----------------
__global__ __launch_bounds__(256)
void gemm2_bt(const unsigned short* __restrict__ Aop, const unsigned short* __restrict__ Bop,
              float* __restrict__ Cout) {
  __shared__ unsigned short As[128 * 32];
  __shared__ unsigned short Bs[128 * 32];
  int t = threadIdx.x;
  int bcol = blockIdx.x * 128;
  int brow = blockIdx.y * 128;
  int wid = t >> 6, lane = t & 63;
  int wr = wid >> 1, wc = wid & 1;
  int lr = lane & 15, kh = lane >> 4;

  const unsigned short* Ag = Aop + (size_t)(brow + wid * 16 + (lane >> 2)) * KR + (lane & 3) * 8;
  const unsigned short* Bg = Bop + (size_t)(bcol + wid * 16 + (lane >> 2)) * KR + (lane & 3) * 8;
  unsigned short* Asl0 = As + wid * 512 + lane * 8;
  unsigned short* Asl1 = As + (wid + 4) * 512 + lane * 8;
  unsigned short* Bsl0 = Bs + wid * 512 + lane * 8;
  unsigned short* Bsl1 = Bs + (wid + 4) * 512 + lane * 8;
  const size_t half = (size_t)64 * KR;

  f32x4_t acc[4][4] = {};

  for (int k0 = 0; k0 < KR; k0 += 32) {
    gload16(Ag + k0, Asl0);
    gload16(Ag + half + k0, Asl1);
    gload16(Bg + k0, Bsl0);
    gload16(Bg + half + k0, Bsl1);
    __syncthreads();
    short8_t af[4], bfv[4];
#pragma unroll
    for (int m = 0; m < 4; ++m)
      af[m] = *(const short8_t*)(As + (wr * 64 + m * 16 + lr) * 32 + kh * 8);
#pragma unroll
    for (int n = 0; n < 4; ++n)
      bfv[n] = *(const short8_t*)(Bs + (wc * 64 + n * 16 + lr) * 32 + kh * 8);
#pragma unroll
    for (int m = 0; m < 4; ++m)
#pragma unroll
      for (int n = 0; n < 4; ++n)
        acc[m][n] = __builtin_amdgcn_mfma_f32_16x16x32_bf16(af[m], bfv[n], acc[m][n], 0, 0, 0);
    __syncthreads();
  }

#pragma unroll
  for (int m = 0; m < 4; ++m) {
    int gr0 = brow + wr * 64 + m * 16 + kh * 4;
#pragma unroll
    for (int n = 0; n < 4; ++n) {
      int gc = bcol + wc * 64 + n * 16 + lr;
#pragma unroll
      for (int j = 0; j < 4; ++j)
        Cout[(size_t)(gr0 + j) * D_DIM + gc] = acc[m][n][j] * SCALE_F;
    }
  }
}

// ---------------- launch ----------------
extern "C" void kernel_launch(void* const* d_in, const int* in_sizes, int n_in,
                              void* d_out, int out_size, void* d_ws, size_t ws_size,
                              hipStream_t stream) {
  const float* x  = (const float*)d_in[0];   // (2,2048,4096)
  const float* A  = (const float*)d_in[1];   // (64,16,4096)
  const float* B  = (const float*)d_in[2];   // (64,4096,16)
  const float* Wr = (const float*)d_in[3];   // (64,4096)
  float* out = (float*)d_out;

  char* ws = (char*)d_ws;
  size_t off = 0;
  auto alloc = [&](size_t bytes) { void* p = ws + off; off += (bytes + 255) & ~255ull; return p; };
  float*          P   = (float*)alloc((size_t)SPLIT_S * N_TOK * K_EXP * 4);   // 16 MB
  float*          G   = (float*)alloc((size_t)N_TOK * K_EXP * 4);             // 1 MB
  unsigned short* Xb  = (unsigned short*)alloc((size_t)N_TOK * D_DIM * 2);    // 32 MB
  unsigned short* Ab  = (unsigned short*)alloc((size_t)KR * D_DIM * 2);       // 8 MB
  unsigned short* Wb  = (unsigned short*)alloc((size_t)D_DIM * KR * 2);       // 8 MB
  unsigned short* Hgb = (unsigned short*)alloc((size_t)N_TOK * KR * 2);       // 8 MB
  float*          Pg  = (float*)alloc((size_t)SPLIT_G * N_TOK * KR * 4);      // 32 MB
  (void)ws_size; (void)in_sizes; (void)n_in; (void)out_size;

  pack_f32_to_bf16<<<1024, 256, 0, stream>>>(A, Ab, KR * D_DIM / 4);
  pack_b_kernel<<<1024, 256, 0, stream>>>(B, Wb, K_EXP * D_DIM * 4);

  scores_mfma<<<dim3(N_TOK / 128, SPLIT_S), 256, 0, stream>>>(x, Wr, P, Xb);
  topk_kernel<<<N_TOK / 4, 256, 0, stream>>>(P, G);

  gemm1_split<<<512, 256, 0, stream>>>(Xb, Ab, Pg);
  reduce_gate_pack<<<N_TOK * KR / 4 / 256, 256, 0, stream>>>(Pg, G, Hgb);

  gemm2_bt<<<dim3(D_DIM / 128, N_TOK / 128), 256, 0, stream>>>(Hgb, Wb, out);
}

// Round 4
// 165.763 us; speedup vs baseline: 2.2597x; 1.0149x over previous
//
#include <hip/hip_runtime.h>

#define D_DIM 4096
#define N_TOK 4096
#define K_EXP 64
#define R_RANK 16
#define KR 1024               // K_EXP * R_RANK
#define SCALE_F 2.0f          // ALPHA / RANK
#define SPLIT_S 16
#define KC_S (D_DIM / SPLIT_S)   // 256
#define SPLIT_G 4
#define KC_G (D_DIM / SPLIT_G)   // 1024

typedef __attribute__((ext_vector_type(8))) short short8_t;   // 8 x bf16
typedef __attribute__((ext_vector_type(4))) float f32x4_t;
typedef __attribute__((ext_vector_type(4))) unsigned short u16x4_t;

__device__ __forceinline__ unsigned short f2bf(float f) {
  unsigned int u = __builtin_bit_cast(unsigned int, f);
  u += 0x7fffu + ((u >> 16) & 1u);          // RTNE
  return (unsigned short)(u >> 16);
}
__device__ __forceinline__ float bf2f(unsigned short h) {
  return __builtin_bit_cast(float, ((unsigned int)h) << 16);
}

// async global->LDS, 16B per lane. LDS dest must be wave-uniform base + lane*16.
__device__ __forceinline__ void gload16(const void* g, void* l) {
  __builtin_amdgcn_global_load_lds(
      (const __attribute__((address_space(1))) unsigned int*)g,
      (__attribute__((address_space(3))) unsigned int*)l, 16, 0, 0);
}

// ---------------- pack kernels ----------------
__global__ void pack_f32_to_bf16(const float* __restrict__ in,
                                 unsigned short* __restrict__ out, int n4) {
  int stride = gridDim.x * blockDim.x;
  for (int i = blockIdx.x * blockDim.x + threadIdx.x; i < n4; i += stride) {
    f32x4_t v = *(const f32x4_t*)(in + (size_t)i * 4);
    u16x4_t o;
    o[0] = f2bf(v[0]); o[1] = f2bf(v[1]); o[2] = f2bf(v[2]); o[3] = f2bf(v[3]);
    *(u16x4_t*)(out + (size_t)i * 4) = o;
  }
}

// B (K,D,R) f32 -> Wb (D, K*R) bf16 : Wb[d][k*16+r] = B[k][d][r]
__global__ void pack_b_kernel(const float* __restrict__ B,
                              unsigned short* __restrict__ Wb, int n) {
  int stride = gridDim.x * blockDim.x;
  for (int i = blockIdx.x * blockDim.x + threadIdx.x; i < n; i += stride) {
    int k   = i >> 14;
    int rem = i & 16383;
    int d   = rem >> 2;
    int r4  = (rem & 3) * 4;
    f32x4_t v = *(const f32x4_t*)(B + ((size_t)(k * D_DIM + d) * R_RANK + r4));
    u16x4_t o;
    o[0] = f2bf(v[0]); o[1] = f2bf(v[1]); o[2] = f2bf(v[2]); o[3] = f2bf(v[3]);
    *(u16x4_t*)(Wb + ((size_t)d * KR + k * R_RANK + r4)) = o;
  }
}

// ---------------- router scores via MFMA (hi/lo bf16 split, split-K=16) ----------------
// Also emits Xb (bf16 hi) for the big GEMM — each (row,k) tile is loaded exactly once here.
__global__ __launch_bounds__(256)
void scores_mfma(const float* __restrict__ x, const float* __restrict__ Wr,
                 float* __restrict__ P, unsigned short* __restrict__ Xb) {
  __shared__ unsigned short Ah[128 * 32];
  __shared__ unsigned short Al[128 * 32];
  __shared__ unsigned short Bh[64 * 32];
  __shared__ unsigned short Bl[64 * 32];
  int t = threadIdx.x;
  int brow = blockIdx.x * 128;
  int kcb = blockIdx.y * KC_S;
  int wid = t >> 6, lane = t & 63;
  int wr = wid >> 1, wc = wid & 1;
  int lr = lane & 15, kh = lane >> 4;

  f32x4_t acc[4][2] = {};

  for (int k0 = kcb; k0 < kcb + KC_S; k0 += 32) {
    f32x4_t av[4];
#pragma unroll
    for (int i = 0; i < 4; ++i) {
      int s = t * 4 + i;                       // row=s>>3 (0..127), col4=(s&7)*4
      av[i] = *(const f32x4_t*)(x + (size_t)(brow + (s >> 3)) * D_DIM + k0 + (s & 7) * 4);
    }
    f32x4_t wv[2];
#pragma unroll
    for (int i = 0; i < 2; ++i) {
      int s = t * 2 + i;                       // row=s>>3 (0..63)
      wv[i] = *(const f32x4_t*)(Wr + (size_t)(s >> 3) * D_DIM + k0 + (s & 7) * 4);
    }
    __syncthreads();                           // prev step's frag reads done
#pragma unroll
    for (int i = 0; i < 4; ++i) {
      int s = t * 4 + i; int row = s >> 3, c = (s & 7) * 4;
      u16x4_t h, l;
#pragma unroll
      for (int j = 0; j < 4; ++j) { h[j] = f2bf(av[i][j]); l[j] = f2bf(av[i][j] - bf2f(h[j])); }
      *(u16x4_t*)(Ah + row * 32 + c) = h;
      *(u16x4_t*)(Al + row * 32 + c) = l;
      *(u16x4_t*)(Xb + (size_t)(brow + row) * D_DIM + k0 + c) = h;   // fused x->bf16 pack
    }
#pragma unroll
    for (int i = 0; i < 2; ++i) {
      int s = t * 2 + i; int row = s >> 3, c = (s & 7) * 4;
      u16x4_t h, l;
#pragma unroll
      for (int j = 0; j < 4; ++j) { h[j] = f2bf(wv[i][j]); l[j] = f2bf(wv[i][j] - bf2f(h[j])); }
      *(u16x4_t*)(Bh + row * 32 + c) = h;
      *(u16x4_t*)(Bl + row * 32 + c) = l;
    }
    __syncthreads();
    short8_t ah[4], al[4], bh[2], bl[2];
#pragma unroll
    for (int m = 0; m < 4; ++m) {
      ah[m] = *(const short8_t*)(Ah + (wr * 64 + m * 16 + lr) * 32 + kh * 8);
      al[m] = *(const short8_t*)(Al + (wr * 64 + m * 16 + lr) * 32 + kh * 8);
    }
#pragma unroll
    for (int n = 0; n < 2; ++n) {
      bh[n] = *(const short8_t*)(Bh + (wc * 32 + n * 16 + lr) * 32 + kh * 8);
      bl[n] = *(const short8_t*)(Bl + (wc * 32 + n * 16 + lr) * 32 + kh * 8);
    }
#pragma unroll
    for (int m = 0; m < 4; ++m)
#pragma unroll
      for (int n = 0; n < 2; ++n) {
        acc[m][n] = __builtin_amdgcn_mfma_f32_16x16x32_bf16(ah[m], bh[n], acc[m][n], 0, 0, 0);
        acc[m][n] = __builtin_amdgcn_mfma_f32_16x16x32_bf16(al[m], bh[n], acc[m][n], 0, 0, 0);
        acc[m][n] = __builtin_amdgcn_mfma_f32_16x16x32_bf16(ah[m], bl[n], acc[m][n], 0, 0, 0);
      }
  }

  float* Pb = P + (size_t)blockIdx.y * N_TOK * K_EXP;
#pragma unroll
  for (int m = 0; m < 4; ++m)
#pragma unroll
    for (int n = 0; n < 2; ++n)
#pragma unroll
      for (int j = 0; j < 4; ++j) {
        int row = brow + wr * 64 + m * 16 + kh * 4 + j;
        int e = wc * 32 + n * 16 + lr;
        Pb[(size_t)row * K_EXP + e] = acc[m][n][j];
      }
}

// ---------------- per-token top-16 + softmax -> dense G (N,64) ----------------
__global__ void topk_kernel(const float* __restrict__ P, float* __restrict__ G) {
  int wid = threadIdx.x >> 6, lane = threadIdx.x & 63;
  int n = blockIdx.x * 4 + wid;
  float rem = 0.f;
#pragma unroll
  for (int c = 0; c < SPLIT_S; ++c)
    rem += P[((size_t)c * N_TOK + n) * K_EXP + lane];
  float topv[16]; int topi[16];
#pragma unroll
  for (int it = 0; it < 16; ++it) {
    float bv = rem; int bi = lane;
#pragma unroll
    for (int off = 32; off >= 1; off >>= 1) {
      float ov = __shfl_xor(bv, off);
      int oi = __shfl_xor(bi, off);
      if (ov > bv || (ov == bv && oi < bi)) { bv = ov; bi = oi; }
    }
    topv[it] = bv; topi[it] = bi;
    if (lane == bi) rem = -1e30f;
  }
  float mx = topv[0];
  float s = 0.f;
#pragma unroll
  for (int j = 0; j < 16; ++j) s += expf(topv[j] - mx);
  float g = 0.f;
#pragma unroll
  for (int j = 0; j < 16; ++j)
    if (topi[j] == lane) g = expf(topv[j] - mx) / s;
  G[(size_t)n * K_EXP + lane] = g;
}

// ---------------- GEMM1 split-K=4: Pgb[z] = bf16(Xb * Ab^T) over K-chunk z ----------------
// 128x128 tile, BK=32, 1024 blocks (8 N x 32 M x 4 z) -> 4 blocks/CU, XCD-bijective swizzle.
__global__ __launch_bounds__(256)
void gemm1_split(const unsigned short* __restrict__ Aop, const unsigned short* __restrict__ Bop,
                 unsigned short* __restrict__ Pgb) {
  __shared__ unsigned short As[128 * 32];
  __shared__ unsigned short Bs[128 * 32];
  int b = blockIdx.x;                       // nwg = 1024, nwg%8==0 -> bijective remap
  int logical = (b & 7) * 128 + (b >> 3);   // XCD gets contiguous 128-chunk of logical
  int zb = logical >> 8;                    // K split (z-major: chunk shares one z-slice)
  int rem = logical & 255;
  int yb = rem >> 3;                        // M-dim (tokens/128)
  int xb = rem & 7;                         // N-dim (KR/128)
  int bcol = xb * 128, brow = yb * 128;
  int kbeg = zb * KC_G;

  int t = threadIdx.x;
  int wid = t >> 6, lane = t & 63;
  int wr = wid >> 1, wc = wid & 1;
  int lr = lane & 15, kh = lane >> 4;

  const unsigned short* Ag = Aop + (size_t)(brow + wid * 16 + (lane >> 2)) * D_DIM + (lane & 3) * 8;
  const unsigned short* Bg = Bop + (size_t)(bcol + wid * 16 + (lane >> 2)) * D_DIM + (lane & 3) * 8;
  unsigned short* Asl0 = As + wid * 512 + lane * 8;
  unsigned short* Asl1 = As + (wid + 4) * 512 + lane * 8;
  unsigned short* Bsl0 = Bs + wid * 512 + lane * 8;
  unsigned short* Bsl1 = Bs + (wid + 4) * 512 + lane * 8;
  const size_t half = (size_t)64 * D_DIM;

  f32x4_t acc[4][4] = {};

  for (int k0 = kbeg; k0 < kbeg + KC_G; k0 += 32) {
    gload16(Ag + k0, Asl0);
    gload16(Ag + half + k0, Asl1);
    gload16(Bg + k0, Bsl0);
    gload16(Bg + half + k0, Bsl1);
    __syncthreads();
    short8_t af[4], bfv[4];
#pragma unroll
    for (int m = 0; m < 4; ++m)
      af[m] = *(const short8_t*)(As + (wr * 64 + m * 16 + lr) * 32 + kh * 8);
#pragma unroll
    for (int n = 0; n < 4; ++n)
      bfv[n] = *(const short8_t*)(Bs + (wc * 64 + n * 16 + lr) * 32 + kh * 8);
#pragma unroll
    for (int m = 0; m < 4; ++m)
#pragma unroll
      for (int n = 0; n < 4; ++n)
        acc[m][n] = __builtin_amdgcn_mfma_f32_16x16x32_bf16(af[m], bfv[n], acc[m][n], 0, 0, 0);
    __syncthreads();
  }

  unsigned short* Pz = Pgb + (size_t)zb * N_TOK * KR;
#pragma unroll
  for (int m = 0; m < 4; ++m) {
    int gr0 = brow + wr * 64 + m * 16 + kh * 4;
#pragma unroll
    for (int n = 0; n < 4; ++n) {
      int gc = bcol + wc * 64 + n * 16 + lr;
#pragma unroll
      for (int j = 0; j < 4; ++j)
        Pz[(size_t)(gr0 + j) * KR + gc] = f2bf(acc[m][n][j]);
    }
  }
}

// ---------------- reduce split-K bf16 partials, apply gate, pack bf16 ----------------
__global__ void reduce_gate_pack(const unsigned short* __restrict__ Pgb,
                                 const float* __restrict__ G,
                                 unsigned short* __restrict__ Hgb) {
  int idx4 = blockIdx.x * blockDim.x + threadIdx.x;   // 1M threads, 4 elems each
  size_t i = (size_t)idx4 * 4;
  int n = (int)(i >> 10);
  int kr = (int)(i & 1023);
  float g = G[(size_t)n * K_EXP + (kr >> 4)];
  float s[4] = {0.f, 0.f, 0.f, 0.f};
#pragma unroll
  for (int z = 0; z < SPLIT_G; ++z) {
    u16x4_t v = *(const u16x4_t*)(Pgb + (size_t)z * N_TOK * KR + i);
#pragma unroll
    for (int j = 0; j < 4; ++j) s[j] += bf2f(v[j]);
  }
  u16x4_t o;
#pragma unroll
  for (int j = 0; j < 4; ++j) o[j] = f2bf(s[j] * g);
  *(u16x4_t*)(Hgb + i) = o;
}

// ---------------- GEMM2: out = SCALE * Hgb(M,KR) * Wb(N,KR)^T, f32 out ----------------
__global__ __launch_bounds__(256)
void gemm2_bt(const unsigned short* __restrict__ Aop, const unsigned short* __restrict__ Bop,
              float* __restrict__ Cout) {
  __shared__ unsigned short As[128 * 32];
  __shared__ unsigned short Bs[128 * 32];
  int t = threadIdx.x;
  int bcol = blockIdx.x * 128;
  int brow = blockIdx.y * 128;
  int wid = t >> 6, lane = t & 63;
  int wr = wid >> 1, wc = wid & 1;
  int lr = lane & 15, kh = lane >> 4;

  const unsigned short* Ag = Aop + (size_t)(brow + wid * 16 + (lane >> 2)) * KR + (lane & 3) * 8;
  const unsigned short* Bg = Bop + (size_t)(bcol + wid * 16 + (lane >> 2)) * KR + (lane & 3) * 8;
  unsigned short* Asl0 = As + wid * 512 + lane * 8;
  unsigned short* Asl1 = As + (wid + 4) * 512 + lane * 8;
  unsigned short* Bsl0 = Bs + wid * 512 + lane * 8;
  unsigned short* Bsl1 = Bs + (wid + 4) * 512 + lane * 8;
  const size_t half = (size_t)64 * KR;

  f32x4_t acc[4][4] = {};

  for (int k0 = 0; k0 < KR; k0 += 32) {
    gload16(Ag + k0, Asl0);
    gload16(Ag + half + k0, Asl1);
    gload16(Bg + k0, Bsl0);
    gload16(Bg + half + k0, Bsl1);
    __syncthreads();
    short8_t af[4], bfv[4];
#pragma unroll
    for (int m = 0; m < 4; ++m)
      af[m] = *(const short8_t*)(As + (wr * 64 + m * 16 + lr) * 32 + kh * 8);
#pragma unroll
    for (int n = 0; n < 4; ++n)
      bfv[n] = *(const short8_t*)(Bs + (wc * 64 + n * 16 + lr) * 32 + kh * 8);
#pragma unroll
    for (int m = 0; m < 4; ++m)
#pragma unroll
      for (int n = 0; n < 4; ++n)
        acc[m][n] = __builtin_amdgcn_mfma_f32_16x16x32_bf16(af[m], bfv[n], acc[m][n], 0, 0, 0);
    __syncthreads();
  }

#pragma unroll
  for (int m = 0; m < 4; ++m) {
    int gr0 = brow + wr * 64 + m * 16 + kh * 4;
#pragma unroll
    for (int n = 0; n < 4; ++n) {
      int gc = bcol + wc * 64 + n * 16 + lr;
#pragma unroll
      for (int j = 0; j < 4; ++j)
        Cout[(size_t)(gr0 + j) * D_DIM + gc] = acc[m][n][j] * SCALE_F;
    }
  }
}

// ---------------- launch ----------------
extern "C" void kernel_launch(void* const* d_in, const int* in_sizes, int n_in,
                              void* d_out, int out_size, void* d_ws, size_t ws_size,
                              hipStream_t stream) {
  const float* x  = (const float*)d_in[0];   // (2,2048,4096)
  const float* A  = (const float*)d_in[1];   // (64,16,4096)
  const float* B  = (const float*)d_in[2];   // (64,4096,16)
  const float* Wr = (const float*)d_in[3];   // (64,4096)
  float* out = (float*)d_out;

  char* ws = (char*)d_ws;
  size_t off = 0;
  auto alloc = [&](size_t bytes) { void* p = ws + off; off += (bytes + 255) & ~255ull; return p; };
  float*          P   = (float*)alloc((size_t)SPLIT_S * N_TOK * K_EXP * 4);   // 16 MB
  float*          G   = (float*)alloc((size_t)N_TOK * K_EXP * 4);             // 1 MB
  unsigned short* Xb  = (unsigned short*)alloc((size_t)N_TOK * D_DIM * 2);    // 32 MB
  unsigned short* Ab  = (unsigned short*)alloc((size_t)KR * D_DIM * 2);       // 8 MB
  unsigned short* Wb  = (unsigned short*)alloc((size_t)D_DIM * KR * 2);       // 8 MB
  unsigned short* Hgb = (unsigned short*)alloc((size_t)N_TOK * KR * 2);       // 8 MB
  unsigned short* Pgb = (unsigned short*)alloc((size_t)SPLIT_G * N_TOK * KR * 2); // 32 MB
  (void)ws_size; (void)in_sizes; (void)n_in; (void)out_size;

  pack_f32_to_bf16<<<1024, 256, 0, stream>>>(A, Ab, KR * D_DIM / 4);
  pack_b_kernel<<<1024, 256, 0, stream>>>(B, Wb, K_EXP * D_DIM * 4);

  scores_mfma<<<dim3(N_TOK / 128, SPLIT_S), 256, 0, stream>>>(x, Wr, P, Xb);
  topk_kernel<<<N_TOK / 4, 256, 0, stream>>>(P, G);

  gemm1_split<<<1024, 256, 0, stream>>>(Xb, Ab, Pgb);
  reduce_gate_pack<<<N_TOK * KR / 4 / 256, 256, 0, stream>>>(Pgb, G, Hgb);

  gemm2_bt<<<dim3(D_DIM / 128, N_TOK / 128), 256, 0, stream>>>(Hgb, Wb, out);
}

// Round 5
// 140.387 us; speedup vs baseline: 2.6682x; 1.1808x over previous
//
#include <hip/hip_runtime.h>

#define D_DIM 4096
#define N_TOK 4096
#define K_EXP 64
#define R_RANK 16
#define KR 1024               // K_EXP * R_RANK
#define SCALE_F 2.0f          // ALPHA / RANK
#define SPLIT_S 16
#define KC_S (D_DIM / SPLIT_S)   // 256
#define SPLIT_G 4
#define KC_G (D_DIM / SPLIT_G)   // 1024

typedef __attribute__((ext_vector_type(8))) short short8_t;   // 8 x bf16
typedef __attribute__((ext_vector_type(4))) float f32x4_t;
typedef __attribute__((ext_vector_type(4))) unsigned short u16x4_t;

__device__ __forceinline__ unsigned short f2bf(float f) {
  unsigned int u = __builtin_bit_cast(unsigned int, f);
  u += 0x7fffu + ((u >> 16) & 1u);          // RTNE
  return (unsigned short)(u >> 16);
}
__device__ __forceinline__ float bf2f(unsigned short h) {
  return __builtin_bit_cast(float, ((unsigned int)h) << 16);
}

// async global->LDS, 16B per lane. LDS dest must be wave-uniform base + lane*16.
__device__ __forceinline__ void gload16(const void* g, void* l) {
  __builtin_amdgcn_global_load_lds(
      (const __attribute__((address_space(1))) unsigned int*)g,
      (__attribute__((address_space(3))) unsigned int*)l, 16, 0, 0);
}

#define BARR() __builtin_amdgcn_s_barrier()
#define FENCE() __builtin_amdgcn_sched_barrier(0)
#define WAIT_LGKM0() asm volatile("s_waitcnt lgkmcnt(0)" ::: "memory")
#define WAIT_VM(n) asm volatile("s_waitcnt vmcnt(" #n ")" ::: "memory")

// ---------------- pack kernels ----------------
__global__ void pack_f32_to_bf16(const float* __restrict__ in,
                                 unsigned short* __restrict__ out, int n4) {
  int stride = gridDim.x * blockDim.x;
  for (int i = blockIdx.x * blockDim.x + threadIdx.x; i < n4; i += stride) {
    f32x4_t v = *(const f32x4_t*)(in + (size_t)i * 4);
    u16x4_t o;
    o[0] = f2bf(v[0]); o[1] = f2bf(v[1]); o[2] = f2bf(v[2]); o[3] = f2bf(v[3]);
    *(u16x4_t*)(out + (size_t)i * 4) = o;
  }
}

// B (K,D,R) f32 -> Wb (D, K*R) bf16 : Wb[d][k*16+r] = B[k][d][r]
__global__ void pack_b_kernel(const float* __restrict__ B,
                              unsigned short* __restrict__ Wb, int n) {
  int stride = gridDim.x * blockDim.x;
  for (int i = blockIdx.x * blockDim.x + threadIdx.x; i < n; i += stride) {
    int k   = i >> 14;
    int rem = i & 16383;
    int d   = rem >> 2;
    int r4  = (rem & 3) * 4;
    f32x4_t v = *(const f32x4_t*)(B + ((size_t)(k * D_DIM + d) * R_RANK + r4));
    u16x4_t o;
    o[0] = f2bf(v[0]); o[1] = f2bf(v[1]); o[2] = f2bf(v[2]); o[3] = f2bf(v[3]);
    *(u16x4_t*)(Wb + ((size_t)d * KR + k * R_RANK + r4)) = o;
  }
}

// ---------------- router scores via MFMA (hi/lo bf16 split, split-K=16) ----------------
__global__ __launch_bounds__(256)
void scores_mfma(const float* __restrict__ x, const float* __restrict__ Wr,
                 float* __restrict__ P, unsigned short* __restrict__ Xb) {
  __shared__ unsigned short Ah[128 * 32];
  __shared__ unsigned short Al[128 * 32];
  __shared__ unsigned short Bh[64 * 32];
  __shared__ unsigned short Bl[64 * 32];
  int t = threadIdx.x;
  int brow = blockIdx.x * 128;
  int kcb = blockIdx.y * KC_S;
  int wid = t >> 6, lane = t & 63;
  int wr = wid >> 1, wc = wid & 1;
  int lr = lane & 15, kh = lane >> 4;

  f32x4_t acc[4][2] = {};

  for (int k0 = kcb; k0 < kcb + KC_S; k0 += 32) {
    f32x4_t av[4];
#pragma unroll
    for (int i = 0; i < 4; ++i) {
      int s = t * 4 + i;
      av[i] = *(const f32x4_t*)(x + (size_t)(brow + (s >> 3)) * D_DIM + k0 + (s & 7) * 4);
    }
    f32x4_t wv[2];
#pragma unroll
    for (int i = 0; i < 2; ++i) {
      int s = t * 2 + i;
      wv[i] = *(const f32x4_t*)(Wr + (size_t)(s >> 3) * D_DIM + k0 + (s & 7) * 4);
    }
    __syncthreads();
#pragma unroll
    for (int i = 0; i < 4; ++i) {
      int s = t * 4 + i; int row = s >> 3, c = (s & 7) * 4;
      u16x4_t h, l;
#pragma unroll
      for (int j = 0; j < 4; ++j) { h[j] = f2bf(av[i][j]); l[j] = f2bf(av[i][j] - bf2f(h[j])); }
      *(u16x4_t*)(Ah + row * 32 + c) = h;
      *(u16x4_t*)(Al + row * 32 + c) = l;
      *(u16x4_t*)(Xb + (size_t)(brow + row) * D_DIM + k0 + c) = h;
    }
#pragma unroll
    for (int i = 0; i < 2; ++i) {
      int s = t * 2 + i; int row = s >> 3, c = (s & 7) * 4;
      u16x4_t h, l;
#pragma unroll
      for (int j = 0; j < 4; ++j) { h[j] = f2bf(wv[i][j]); l[j] = f2bf(wv[i][j] - bf2f(h[j])); }
      *(u16x4_t*)(Bh + row * 32 + c) = h;
      *(u16x4_t*)(Bl + row * 32 + c) = l;
    }
    __syncthreads();
    short8_t ah[4], al[4], bh[2], bl[2];
#pragma unroll
    for (int m = 0; m < 4; ++m) {
      ah[m] = *(const short8_t*)(Ah + (wr * 64 + m * 16 + lr) * 32 + kh * 8);
      al[m] = *(const short8_t*)(Al + (wr * 64 + m * 16 + lr) * 32 + kh * 8);
    }
#pragma unroll
    for (int n = 0; n < 2; ++n) {
      bh[n] = *(const short8_t*)(Bh + (wc * 32 + n * 16 + lr) * 32 + kh * 8);
      bl[n] = *(const short8_t*)(Bl + (wc * 32 + n * 16 + lr) * 32 + kh * 8);
    }
#pragma unroll
    for (int m = 0; m < 4; ++m)
#pragma unroll
      for (int n = 0; n < 2; ++n) {
        acc[m][n] = __builtin_amdgcn_mfma_f32_16x16x32_bf16(ah[m], bh[n], acc[m][n], 0, 0, 0);
        acc[m][n] = __builtin_amdgcn_mfma_f32_16x16x32_bf16(al[m], bh[n], acc[m][n], 0, 0, 0);
        acc[m][n] = __builtin_amdgcn_mfma_f32_16x16x32_bf16(ah[m], bl[n], acc[m][n], 0, 0, 0);
      }
  }

  float* Pb = P + (size_t)blockIdx.y * N_TOK * K_EXP;
#pragma unroll
  for (int m = 0; m < 4; ++m)
#pragma unroll
    for (int n = 0; n < 2; ++n)
#pragma unroll
      for (int j = 0; j < 4; ++j) {
        int row = brow + wr * 64 + m * 16 + kh * 4 + j;
        int e = wc * 32 + n * 16 + lr;
        Pb[(size_t)row * K_EXP + e] = acc[m][n][j];
      }
}

// ---------------- per-token top-16 + softmax -> dense G (N,64) ----------------
__global__ void topk_kernel(const float* __restrict__ P, float* __restrict__ G) {
  int wid = threadIdx.x >> 6, lane = threadIdx.x & 63;
  int n = blockIdx.x * 4 + wid;
  float rem = 0.f;
#pragma unroll
  for (int c = 0; c < SPLIT_S; ++c)
    rem += P[((size_t)c * N_TOK + n) * K_EXP + lane];
  float topv[16]; int topi[16];
#pragma unroll
  for (int it = 0; it < 16; ++it) {
    float bv = rem; int bi = lane;
#pragma unroll
    for (int off = 32; off >= 1; off >>= 1) {
      float ov = __shfl_xor(bv, off);
      int oi = __shfl_xor(bi, off);
      if (ov > bv || (ov == bv && oi < bi)) { bv = ov; bi = oi; }
    }
    topv[it] = bv; topi[it] = bi;
    if (lane == bi) rem = -1e30f;
  }
  float mx = topv[0];
  float s = 0.f;
#pragma unroll
  for (int j = 0; j < 16; ++j) s += expf(topv[j] - mx);
  float g = 0.f;
#pragma unroll
  for (int j = 0; j < 16; ++j)
    if (topi[j] == lane) g = expf(topv[j] - mx) / s;
  G[(size_t)n * K_EXP + lane] = g;
}

// ---------------- 8-phase 256x256 MFMA GEMM (C = A(M,KD-slice) * B(N,KD-slice)^T) ----
// 512 thr = 8 waves (2M x 4N), BK=64, 16 K-tiles/block, 2 LDS buffers (128 KiB).
// T2 swizzle: linear gload_lds dest + inverse-permuted global src + XOR'd ds_read.
// Stage schedule (group t = 4 phases computing tile t from buf[t&1]):
//   p0: stage A1,A3(t+1)->buf[(t+1)&1]   (region last read group t-1 p3)
//   p1: stage B0,B1(t+2)->buf[t&1]; vmcnt(10)  (B last read this group p0)
//   p2: stage B2,B3(t+2)
//   p3: stage A0,A2(t+2); vmcnt(8)       (A0/A2 last read this group p1)
// Deadlines: B/A0/A2(t) by t.p0 (vmcnt(8)@(t-1).p3); A1/A3(t) by t.p2 (vmcnt(10)@t.p1).
template <int KD, int EPI>   // EPI 0: bf16 partial out (stride KR); 1: f32*SCALE (stride D_DIM)
__global__ __launch_bounds__(512, 2)
void gemm8ph(const unsigned short* __restrict__ Aop,
             const unsigned short* __restrict__ Bop,
             void* __restrict__ Cout) {
  extern __shared__ unsigned short lds[];   // 2 x (A 256x64 + B 256x64) = 65536 shorts
  const int t = threadIdx.x;
  const int wid = t >> 6, lane = t & 63;
  const int wm = wid >> 2, wn = wid & 3;
  const int lr = lane & 15, kh = lane >> 4;

  int brow, bcol, kbeg;
  unsigned short* outb = nullptr;
  float* outf = nullptr;
  {
    int b = blockIdx.x;                    // 256 blocks, XCD-bijective remap
    int logical = (b & 7) * 32 + (b >> 3);
    if constexpr (EPI == 0) {
      int zb = logical >> 6;               // K split (4)
      int rem = logical & 63;
      brow = (rem >> 2) * 256;
      bcol = (rem & 3) * 256;
      kbeg = zb * KC_G;
      outb = (unsigned short*)Cout + (size_t)zb * N_TOK * KR;
    } else {
      brow = (logical >> 4) * 256;
      bcol = (logical & 15) * 256;
      kbeg = 0;
      outf = (float*)Cout;
    }
  }

  // staging: thread tau covers unit-linear LDS [tau*8, tau*8+8) shorts;
  // source col chunk permuted by (row&7) so swizzled READ sees logical layout.
  const int srow = t >> 3;                               // 0..63 within unit
  const int scoff = (((t & 7) ^ (srow & 7)) * 8);        // shorts
  const int ldoff = t * 8;                               // shorts
  const unsigned short* Abase = Aop + (size_t)(brow + srow) * KD + kbeg + scoff;
  const unsigned short* Bbase = Bop + (size_t)(bcol + srow) * KD + kbeg + scoff;

  auto stA = [&](int j, int T) {
    gload16(Abase + (size_t)j * 64 * KD + T * 64,
            lds + (T & 1) * 32768 + j * 4096 + ldoff);
  };
  auto stB = [&](int j, int T) {
    gload16(Bbase + (size_t)j * 64 * KD + T * 64,
            lds + (T & 1) * 32768 + 16384 + j * 4096 + ldoff);
  };
  // fragment reads (XOR-swizzled)
  auto rdA = [&](const unsigned short* LA, int m, int ks) -> short8_t {
    int r = wm * 128 + m * 16 + lr;
    int x = (ks * 32 + kh * 8) ^ ((lr & 7) << 3);
    return *(const short8_t*)(LA + r * 64 + x);
  };
  auto rdB = [&](const unsigned short* LB, int n, int ks) -> short8_t {
    int r = wn * 64 + n * 16 + lr;
    int x = (ks * 32 + kh * 8) ^ ((lr & 7) << 3);
    return *(const short8_t*)(LB + r * 64 + x);
  };

  f32x4_t acc[8][4] = {};
  short8_t bq[4][2], aq[2][2];

#define MFMA_QUAD(mb)                                                        \
  _Pragma("unroll")                                                          \
  for (int mm = 0; mm < 2; ++mm)                                             \
    _Pragma("unroll")                                                        \
    for (int n = 0; n < 4; ++n)                                              \
      _Pragma("unroll")                                                      \
      for (int ks = 0; ks < 2; ++ks)                                         \
        acc[(mb) + mm][n] = __builtin_amdgcn_mfma_f32_16x16x32_bf16(         \
            aq[mm][ks], bq[n][ks], acc[(mb) + mm][n], 0, 0, 0);

  // ---- prologue: tile0 full (8 units), tile1 B*,A0,A2 (6 units) = 14 loads
  stB(0, 0); stB(1, 0); stB(2, 0); stB(3, 0);
  stA(0, 0); stA(1, 0); stA(2, 0); stA(3, 0);
  stB(0, 1); stB(1, 1); stB(2, 1); stB(3, 1);
  stA(0, 1); stA(2, 1);
  WAIT_VM(6);                      // oldest 8 (tile 0) landed
  FENCE(); BARR(); FENCE();

  for (int tt = 0; tt < 16; ++tt) {
    const unsigned short* LA = lds + (tt & 1) * 32768;
    const unsigned short* LB = LA + 16384;
    // ---------- phase 0: all B frags + A m0,1 ----------
#pragma unroll
    for (int n = 0; n < 4; ++n) { bq[n][0] = rdB(LB, n, 0); bq[n][1] = rdB(LB, n, 1); }
    aq[0][0] = rdA(LA, 0, 0); aq[0][1] = rdA(LA, 0, 1);
    aq[1][0] = rdA(LA, 1, 0); aq[1][1] = rdA(LA, 1, 1);
    if (tt + 1 < 16) { stA(1, tt + 1); stA(3, tt + 1); }
    FENCE(); BARR(); WAIT_LGKM0(); FENCE();
    __builtin_amdgcn_s_setprio(1);
    MFMA_QUAD(0)
    __builtin_amdgcn_s_setprio(0);
    FENCE(); BARR(); FENCE();
    // ---------- phase 1: A m2,3 ----------
    aq[0][0] = rdA(LA, 2, 0); aq[0][1] = rdA(LA, 2, 1);
    aq[1][0] = rdA(LA, 3, 0); aq[1][1] = rdA(LA, 3, 1);
    if (tt + 2 < 16) { stB(0, tt + 2); stB(1, tt + 2); }
    WAIT_VM(10);
    FENCE(); BARR(); WAIT_LGKM0(); FENCE();
    __builtin_amdgcn_s_setprio(1);
    MFMA_QUAD(2)
    __builtin_amdgcn_s_setprio(0);
    FENCE(); BARR(); FENCE();
    // ---------- phase 2: A m4,5 ----------
    aq[0][0] = rdA(LA, 4, 0); aq[0][1] = rdA(LA, 4, 1);
    aq[1][0] = rdA(LA, 5, 0); aq[1][1] = rdA(LA, 5, 1);
    if (tt + 2 < 16) { stB(2, tt + 2); stB(3, tt + 2); }
    FENCE(); BARR(); WAIT_LGKM0(); FENCE();
    __builtin_amdgcn_s_setprio(1);
    MFMA_QUAD(4)
    __builtin_amdgcn_s_setprio(0);
    FENCE(); BARR(); FENCE();
    // ---------- phase 3: A m6,7 ----------
    aq[0][0] = rdA(LA, 6, 0); aq[0][1] = rdA(LA, 6, 1);
    aq[1][0] = rdA(LA, 7, 0); aq[1][1] = rdA(LA, 7, 1);
    if (tt + 2 < 16) { stA(0, tt + 2); stA(2, tt + 2); }
    WAIT_VM(8);
    FENCE(); BARR(); WAIT_LGKM0(); FENCE();
    __builtin_amdgcn_s_setprio(1);
    MFMA_QUAD(6)
    __builtin_amdgcn_s_setprio(0);
    FENCE(); BARR(); FENCE();
  }
#undef MFMA_QUAD

  // ---- epilogue ----
#pragma unroll
  for (int m = 0; m < 8; ++m) {
    int gr0 = brow + wm * 128 + m * 16 + kh * 4;
#pragma unroll
    for (int n = 0; n < 4; ++n) {
      int gc = bcol + wn * 64 + n * 16 + lr;
#pragma unroll
      for (int j = 0; j < 4; ++j) {
        if constexpr (EPI == 0)
          outb[(size_t)(gr0 + j) * KR + gc] = f2bf(acc[m][n][j]);
        else
          outf[(size_t)(gr0 + j) * D_DIM + gc] = acc[m][n][j] * SCALE_F;
      }
    }
  }
}

// ---------------- reduce split-K bf16 partials, apply gate, pack bf16 ----------------
__global__ void reduce_gate_pack(const unsigned short* __restrict__ Pgb,
                                 const float* __restrict__ G,
                                 unsigned short* __restrict__ Hgb) {
  int idx4 = blockIdx.x * blockDim.x + threadIdx.x;
  size_t i = (size_t)idx4 * 4;
  int n = (int)(i >> 10);
  int kr = (int)(i & 1023);
  float g = G[(size_t)n * K_EXP + (kr >> 4)];
  float s[4] = {0.f, 0.f, 0.f, 0.f};
#pragma unroll
  for (int z = 0; z < SPLIT_G; ++z) {
    u16x4_t v = *(const u16x4_t*)(Pgb + (size_t)z * N_TOK * KR + i);
#pragma unroll
    for (int j = 0; j < 4; ++j) s[j] += bf2f(v[j]);
  }
  u16x4_t o;
#pragma unroll
  for (int j = 0; j < 4; ++j) o[j] = f2bf(s[j] * g);
  *(u16x4_t*)(Hgb + i) = o;
}

// ---------------- launch ----------------
extern "C" void kernel_launch(void* const* d_in, const int* in_sizes, int n_in,
                              void* d_out, int out_size, void* d_ws, size_t ws_size,
                              hipStream_t stream) {
  const float* x  = (const float*)d_in[0];   // (2,2048,4096)
  const float* A  = (const float*)d_in[1];   // (64,16,4096)
  const float* B  = (const float*)d_in[2];   // (64,4096,16)
  const float* Wr = (const float*)d_in[3];   // (64,4096)
  float* out = (float*)d_out;

  char* ws = (char*)d_ws;
  size_t off = 0;
  auto alloc = [&](size_t bytes) { void* p = ws + off; off += (bytes + 255) & ~255ull; return p; };
  float*          P   = (float*)alloc((size_t)SPLIT_S * N_TOK * K_EXP * 4);   // 16 MB
  float*          G   = (float*)alloc((size_t)N_TOK * K_EXP * 4);             // 1 MB
  unsigned short* Xb  = (unsigned short*)alloc((size_t)N_TOK * D_DIM * 2);    // 32 MB
  unsigned short* Ab  = (unsigned short*)alloc((size_t)KR * D_DIM * 2);       // 8 MB
  unsigned short* Wb  = (unsigned short*)alloc((size_t)D_DIM * KR * 2);       // 8 MB
  unsigned short* Hgb = (unsigned short*)alloc((size_t)N_TOK * KR * 2);       // 8 MB
  unsigned short* Pgb = (unsigned short*)alloc((size_t)SPLIT_G * N_TOK * KR * 2); // 32 MB
  (void)ws_size; (void)in_sizes; (void)n_in; (void)out_size;

  // allow 128 KiB dynamic LDS (host-side attribute, idempotent, not a stream op)
  (void)hipFuncSetAttribute((const void*)&gemm8ph<D_DIM, 0>,
                            hipFuncAttributeMaxDynamicSharedMemorySize, 131072);
  (void)hipFuncSetAttribute((const void*)&gemm8ph<KR, 1>,
                            hipFuncAttributeMaxDynamicSharedMemorySize, 131072);

  pack_f32_to_bf16<<<1024, 256, 0, stream>>>(A, Ab, KR * D_DIM / 4);
  pack_b_kernel<<<1024, 256, 0, stream>>>(B, Wb, K_EXP * D_DIM * 4);

  scores_mfma<<<dim3(N_TOK / 128, SPLIT_S), 256, 0, stream>>>(x, Wr, P, Xb);
  topk_kernel<<<N_TOK / 4, 256, 0, stream>>>(P, G);

  // GEMM1: Pgb[z] = bf16(Xb @ Ab^T) over K-chunk z  (256 blocks: 16M x 4N x 4z)
  gemm8ph<D_DIM, 0><<<256, 512, 131072, stream>>>(Xb, Ab, Pgb);
  reduce_gate_pack<<<N_TOK * KR / 4 / 256, 256, 0, stream>>>(Pgb, G, Hgb);

  // GEMM2: out = SCALE * Hgb @ Wb^T  (256 blocks: 16M x 16N)
  gemm8ph<KR, 1><<<256, 512, 131072, stream>>>(Hgb, Wb, out);
}